// Round 1
// baseline (91.537 us; speedup 1.0000x reference)
//
#include <hip/hip_runtime.h>
#include <hip/hip_bf16.h>
#include <math.h>

#define N_AUDIO 32768
#define NB 8
#define NC 128
#define NT 128
#define NO 128

// ws layout:
//   SEG : float4[NB][NT][NO]  (f, df, a, da)   = 8*128*128*16 B = 2 MiB
//   CW  : float [NB][NT][NO]  (C_i mod 2)      = 512 KiB

__global__ __launch_bounds__(128)
void prep_kernel(const float* __restrict__ x,
                 const float* __restrict__ amp_w,
                 const float* __restrict__ amp_b,
                 const float* __restrict__ freq_w,
                 const float* __restrict__ freq_b,
                 float4* __restrict__ SEG,
                 float*  __restrict__ CW)
{
    const int bo = blockIdx.x;            // 0..1023
    const int b  = bo >> 7;
    const int o  = bo & 127;
    const int t  = threadIdx.x;           // knot index 0..127

    const float* xp = x + b * (NC * NT) + t;   // x[b, c, t], stride NT per c
    const float* wa = amp_w  + o * NC;
    const float* wf = freq_w + o * NC;

    float va = 0.f, vf = 0.f;
#pragma unroll 8
    for (int c = 0; c < NC; ++c) {
        float xv = xp[c * NT];
        va = fmaf(xv, wa[c], va);
        vf = fmaf(xv, wf[c], vf);
    }
    va += amp_b[o];
    vf += freq_b[o];
    const float sa = 1.f / (1.f + __expf(-va));   // amp knot
    const float sf = 1.f / (1.f + __expf(-vf));   // freq knot

    __shared__ float  fsh[NT];
    __shared__ float  ash[NT];
    __shared__ double psh[NT];
    fsh[t] = sf;
    ash[t] = sa;
    psh[t] = (double)sf;
    __syncthreads();

    // Hillis-Steele inclusive scan (double) over the 128 freq knots
    for (int off = 1; off < NT; off <<= 1) {
        double add = (t >= off) ? psh[t - off] : 0.0;
        double v   = psh[t];
        __syncthreads();
        psh[t] = v + add;
        __syncthreads();
    }
    const double incl = psh[t];
    const double excl = incl - (double)sf;
    // C_i = 256 * sum_{s<i} f_s + 128 * f_i   (phase/pi at start of segment i)
    double Cd = 256.0 * excl + 128.0 * (double)sf;
    Cd = fmod(Cd, 2.0);                   // sin(pi*z) has period 2 in z

    const float df = (t < NT - 1) ? (fsh[t + 1] - sf) : 0.f;
    const float da = (t < NT - 1) ? (ash[t + 1] - sa) : 0.f;

    const int idx = (b * NT + t) * NO + o;   // [b][i][o] layout
    SEG[idx] = make_float4(sf, df, sa, da);
    CW[idx]  = (float)Cd;
}

__global__ __launch_bounds__(256)
void synth_kernel(const float4* __restrict__ SEG,
                  const float*  __restrict__ CW,
                  float* __restrict__ out)
{
    const int j = blockIdx.x * 256 + threadIdx.x;   // 0..32767
    const int b = blockIdx.y;

    // Segment decode. Boundaries are at j = 128 + 256*i (64-aligned), so every
    // wave is segment-uniform -> per-o loads below are wave-uniform.
    int   i;
    float m, mask;
    if (j < 128)          { i = 0;   m = (float)(j - 127);   mask = 0.f; }  // head: clip, z = C0 + m*f0, m<=0
    else if (j >= 32640)  { i = 127; m = (float)(j - 32639); mask = 0.f; }  // tail: df=da=0 anyway
    else {
        const int jj = j - 128;
        i    = jj >> 8;
        m    = (float)((jj & 255) + 1);
        mask = 1.f;
    }

    const float m2s = m * m * (1.f / 512.f) * mask;      // quadratic phase term coeff
    const float wA  = (m - 0.5f) * (1.f / 256.f) * mask; // amp interp weight

    const float4* seg  = SEG + (b * NT + i) * NO;
    const float*  crow = CW  + (b * NT + i) * NO;

    float sum = 0.f;
#pragma unroll 4
    for (int o = 0; o < NO; ++o) {
        const float4 s  = seg[o];    // {f, df, a, da}
        const float  Cv = crow[o];
        const float  z   = fmaf(s.y, m2s, fmaf(m, s.x, Cv));  // phase / pi
        const float  amp = fmaf(s.w, wA, s.z);
        float tt = z * 0.5f;                 // revolutions
        tt -= floorf(tt);                    // reduce to [0,1)
        sum = fmaf(amp, __builtin_amdgcn_sinf(tt), sum);  // v_sin_f32: sin(2*pi*tt)
    }
    out[b * N_AUDIO + j] = sum * (1.f / 128.f);
}

extern "C" void kernel_launch(void* const* d_in, const int* in_sizes, int n_in,
                              void* d_out, int out_size, void* d_ws, size_t ws_size,
                              hipStream_t stream)
{
    const float* x      = (const float*)d_in[0];
    const float* amp_w  = (const float*)d_in[1];
    const float* amp_b  = (const float*)d_in[2];
    const float* freq_w = (const float*)d_in[3];
    const float* freq_b = (const float*)d_in[4];
    float* out = (float*)d_out;

    float4* SEG = (float4*)d_ws;
    float*  CW  = (float*)((char*)d_ws + (size_t)NB * NT * NO * sizeof(float4));

    prep_kernel<<<dim3(NB * NO), dim3(128), 0, stream>>>(
        x, amp_w, amp_b, freq_w, freq_b, SEG, CW);
    synth_kernel<<<dim3(N_AUDIO / 256, NB), dim3(256), 0, stream>>>(SEG, CW, out);
}

// Round 2
// 80.976 us; speedup vs baseline: 1.1304x; 1.1304x over previous
//
#include <hip/hip_runtime.h>
#include <hip/hip_bf16.h>
#include <math.h>

#define N_AUDIO 32768
#define NB 8
#define NC 128
#define NT 128
#define NO 128

// ws layout:
//   SEG : float4[NB][NT][NO]  (f, df, a, da)   = 8*128*128*16 B = 2 MiB
//   CW  : float [NB][NT][NO]  (C_i mod 2)      = 512 KiB

__global__ __launch_bounds__(128)
void prep_kernel(const float* __restrict__ x,
                 const float* __restrict__ amp_w,
                 const float* __restrict__ amp_b,
                 const float* __restrict__ freq_w,
                 const float* __restrict__ freq_b,
                 float4* __restrict__ SEG,
                 float*  __restrict__ CW)
{
    const int bo = blockIdx.x;            // 0..1023
    const int b  = bo >> 7;
    const int o  = bo & 127;
    const int t  = threadIdx.x;           // knot index 0..127

    const float* xp = x + b * (NC * NT) + t;   // x[b, c, t], stride NT per c
    const float* wa = amp_w  + o * NC;
    const float* wf = freq_w + o * NC;

    float va = 0.f, vf = 0.f;
#pragma unroll 8
    for (int c = 0; c < NC; ++c) {
        float xv = xp[c * NT];
        va = fmaf(xv, wa[c], va);
        vf = fmaf(xv, wf[c], vf);
    }
    va += amp_b[o];
    vf += freq_b[o];
    const float sa = 1.f / (1.f + __expf(-va));   // amp knot
    const float sf = 1.f / (1.f + __expf(-vf));   // freq knot

    __shared__ float  fsh[NT];
    __shared__ float  ash[NT];
    __shared__ double psh[NT];
    fsh[t] = sf;
    ash[t] = sa;
    psh[t] = (double)sf;
    __syncthreads();

    // Hillis-Steele inclusive scan (double) over the 128 freq knots
    for (int off = 1; off < NT; off <<= 1) {
        double add = (t >= off) ? psh[t - off] : 0.0;
        double v   = psh[t];
        __syncthreads();
        psh[t] = v + add;
        __syncthreads();
    }
    const double incl = psh[t];
    const double excl = incl - (double)sf;
    // C_i = 256 * sum_{s<i} f_s + 128 * f_i   (phase/pi at start of segment i)
    double Cd = 256.0 * excl + 128.0 * (double)sf;
    Cd -= 2.0 * floor(Cd * 0.5);          // mod 2 (sin(pi*z) has period 2 in z)

    const float df = (t < NT - 1) ? (fsh[t + 1] - sf) : 0.f;
    const float da = (t < NT - 1) ? (ash[t + 1] - sa) : 0.f;

    const int idx = (b * NT + t) * NO + o;   // [b][i][o] layout
    SEG[idx] = make_float4(sf, df, sa, da);
    CW[idx]  = (float)Cd;
}

__global__ __launch_bounds__(256)
void synth_kernel(const float4* __restrict__ SEG,
                  const float*  __restrict__ CW,
                  float* __restrict__ out)
{
    const int j = blockIdx.x * 256 + threadIdx.x;   // 0..32767
    const int b = blockIdx.y;

    // Segment decode. Boundaries are at j = 128 + 256*i, so i is constant per
    // half-block (threads 0..127 -> blockIdx-1, 128..255 -> blockIdx): every
    // wave is segment-uniform. readfirstlane makes that provable -> SGPR base
    // -> compiler emits scalar (s_load) batched loads instead of per-lane VMEM.
    int   i;
    float m, mask;
    if (j < 128)          { i = 0;   m = (float)(j - 127);   mask = 0.f; }  // head: clip, z = C0 + m*f0, m<=0
    else if (j >= 32640)  { i = 127; m = (float)(j - 32639); mask = 0.f; }  // tail: df=da=0 anyway
    else {
        const int jj = j - 128;
        i    = jj >> 8;
        m    = (float)((jj & 255) + 1);
        mask = 1.f;
    }
    i = __builtin_amdgcn_readfirstlane(i);

    const float m2s = m * m * (1.f / 512.f) * mask;      // quadratic phase term coeff
    const float wA  = (m - 0.5f) * (1.f / 256.f) * mask; // amp interp weight

    const float4* __restrict__ seg  = SEG + (b * NT + i) * NO;
    const float*  __restrict__ crow = CW  + (b * NT + i) * NO;

    float sum0 = 0.f, sum1 = 0.f;
#pragma unroll 8
    for (int o = 0; o < NO; o += 2) {
        const float4 s0 = seg[o];
        const float4 s1 = seg[o + 1];
        const float  C0 = crow[o];
        const float  C1 = crow[o + 1];
        float z0 = fmaf(s0.y, m2s, fmaf(m, s0.x, C0));   // phase / pi
        float z1 = fmaf(s1.y, m2s, fmaf(m, s1.x, C1));
        float a0 = fmaf(s0.w, wA, s0.z);
        float a1 = fmaf(s1.w, wA, s1.z);
        float t0 = z0 * 0.5f; t0 -= floorf(t0);          // revolutions in [0,1)
        float t1 = z1 * 0.5f; t1 -= floorf(t1);
        sum0 = fmaf(a0, __builtin_amdgcn_sinf(t0), sum0);
        sum1 = fmaf(a1, __builtin_amdgcn_sinf(t1), sum1);
    }
    out[b * N_AUDIO + j] = (sum0 + sum1) * (1.f / 128.f);
}

extern "C" void kernel_launch(void* const* d_in, const int* in_sizes, int n_in,
                              void* d_out, int out_size, void* d_ws, size_t ws_size,
                              hipStream_t stream)
{
    const float* x      = (const float*)d_in[0];
    const float* amp_w  = (const float*)d_in[1];
    const float* amp_b  = (const float*)d_in[2];
    const float* freq_w = (const float*)d_in[3];
    const float* freq_b = (const float*)d_in[4];
    float* out = (float*)d_out;

    float4* SEG = (float4*)d_ws;
    float*  CW  = (float*)((char*)d_ws + (size_t)NB * NT * NO * sizeof(float4));

    prep_kernel<<<dim3(NB * NO), dim3(128), 0, stream>>>(
        x, amp_w, amp_b, freq_w, freq_b, SEG, CW);
    synth_kernel<<<dim3(N_AUDIO / 256, NB), dim3(256), 0, stream>>>(SEG, CW, out);
}

// Round 3
// 80.410 us; speedup vs baseline: 1.1384x; 1.0070x over previous
//
#include <hip/hip_runtime.h>
#include <hip/hip_bf16.h>
#include <math.h>

#define N_AUDIO 32768
#define NB 8
#define NC 128
#define NT 128
#define NO 128

// ws layout:
//   SEG : float4[NB][NT][NO]  (f/2, df/1024, a/128, da/128)  = 2 MiB
//   CW  : float [NB][NT][NO]  ((C_i/2) mod 1, revolutions)   = 512 KiB
// z_rev(m) = CW + m*(f/2) + m^2*(df/1024); audio = sum_o amp'(m)*sin(2*pi*fract(z_rev))

__global__ __launch_bounds__(128)
void prep_kernel(const float* __restrict__ x,
                 const float* __restrict__ amp_w,
                 const float* __restrict__ amp_b,
                 const float* __restrict__ freq_w,
                 const float* __restrict__ freq_b,
                 float4* __restrict__ SEG,
                 float*  __restrict__ CW)
{
    const int bo = blockIdx.x;            // 0..1023
    const int b  = bo >> 7;
    const int o  = bo & 127;
    const int t  = threadIdx.x;           // knot index 0..127

    const float* xp = x + b * (NC * NT) + t;   // x[b, c, t], stride NT per c
    const float* wa = amp_w  + o * NC;
    const float* wf = freq_w + o * NC;

    float va = 0.f, vf = 0.f;
#pragma unroll 8
    for (int c = 0; c < NC; ++c) {
        float xv = xp[c * NT];
        va = fmaf(xv, wa[c], va);
        vf = fmaf(xv, wf[c], vf);
    }
    va += amp_b[o];
    vf += freq_b[o];
    const float sa = 1.f / (1.f + __expf(-va));   // amp knot
    const float sf = 1.f / (1.f + __expf(-vf));   // freq knot

    __shared__ float  fsh[NT];
    __shared__ float  ash[NT];
    __shared__ double psh[NT];
    fsh[t] = sf;
    ash[t] = sa;
    psh[t] = (double)sf;
    __syncthreads();

    // Hillis-Steele inclusive scan (double) over the 128 freq knots
    for (int off = 1; off < NT; off <<= 1) {
        double add = (t >= off) ? psh[t - off] : 0.0;
        double v   = psh[t];
        __syncthreads();
        psh[t] = v + add;
        __syncthreads();
    }
    const double incl = psh[t];
    const double excl = incl - (double)sf;
    // C_i (rev) = 128 * sum_{s<i} f_s + 64 * f_i  (phase/2pi at segment start)
    double Cd = 128.0 * excl + 64.0 * (double)sf;
    Cd -= floor(Cd);                      // mod 1 revolution

    const float df = (t < NT - 1) ? (fsh[t + 1] - sf) : 0.f;
    const float da = (t < NT - 1) ? (ash[t + 1] - sa) : 0.f;

    const int idx = (b * NT + t) * NO + o;   // [b][i][o] layout
    SEG[idx] = make_float4(0.5f * sf,              // m coefficient (rev)
                           df * (1.f / 1024.f),    // m^2 coefficient (rev)
                           sa * (1.f / 128.f),     // amp / 128 (mean folded in)
                           da * (1.f / 128.f));    // damp / 128
    CW[idx]  = (float)Cd;
}

__global__ __launch_bounds__(256)
void synth_kernel(const float4* __restrict__ SEG,
                  const float*  __restrict__ CW,
                  float* __restrict__ out)
{
    const int k   = blockIdx.x;           // 0..127: samples [256k, 256k+256)
    const int b   = blockIdx.y;
    const int tid = threadIdx.x;
    const int j   = k * 256 + tid;

    // Block covers two segment rows: row0 = k-1 (lower 128 samples),
    // row1 = k (upper 128). Block 0's lower half is the clipped head -> uses
    // row 0 with mask=0. Tail (block 127 upper) is generic since df=da=0.
    __shared__ float4 sP[2][NO];
    __shared__ float  sC[2][NO];
    {
        const int h   = tid >> 7;         // 0 -> row0, 1 -> row1
        const int oo  = tid & 127;
        const int row = h ? k : (k > 0 ? k - 1 : 0);
        const int base = (b * NT + row) * NO;
        sP[h][oo] = SEG[base + oo];
        sC[h][oo] = CW[base + oo];
    }
    __syncthreads();

    float m, mask;
    if (j < 128) { m = (float)(j - 127); mask = 0.f; }              // head
    else         { m = (float)(((j - 128) & 255) + 1); mask = 1.f; } // generic
    const float m2 = m * m * mask;                    // kills quadratic in head
    const float wA = (m - 0.5f) * (1.f / 256.f) * mask;

    const int h = tid >> 7;               // wave-uniform
    const float4* __restrict__ P = sP[h];
    const float*  __restrict__ C = sC[h];

    float sum0 = 0.f, sum1 = 0.f;
#pragma unroll 4
    for (int o = 0; o < NO; o += 2) {
        // all 64 lanes of a wave read the SAME LDS address -> broadcast, free
        const float4 p0 = P[o];
        const float4 p1 = P[o + 1];
        const float  c0 = C[o];
        const float  c1 = C[o + 1];
        const float z0 = fmaf(m2, p0.y, fmaf(m, p0.x, c0));  // revolutions
        const float z1 = fmaf(m2, p1.y, fmaf(m, p1.x, c1));
        const float a0 = fmaf(wA, p0.w, p0.z);
        const float a1 = fmaf(wA, p1.w, p1.z);
        sum0 = fmaf(a0, __builtin_amdgcn_sinf(__builtin_amdgcn_fractf(z0)), sum0);
        sum1 = fmaf(a1, __builtin_amdgcn_sinf(__builtin_amdgcn_fractf(z1)), sum1);
    }
    out[b * N_AUDIO + j] = sum0 + sum1;
}

extern "C" void kernel_launch(void* const* d_in, const int* in_sizes, int n_in,
                              void* d_out, int out_size, void* d_ws, size_t ws_size,
                              hipStream_t stream)
{
    const float* x      = (const float*)d_in[0];
    const float* amp_w  = (const float*)d_in[1];
    const float* amp_b  = (const float*)d_in[2];
    const float* freq_w = (const float*)d_in[3];
    const float* freq_b = (const float*)d_in[4];
    float* out = (float*)d_out;

    float4* SEG = (float4*)d_ws;
    float*  CW  = (float*)((char*)d_ws + (size_t)NB * NT * NO * sizeof(float4));

    prep_kernel<<<dim3(NB * NO), dim3(128), 0, stream>>>(
        x, amp_w, amp_b, freq_w, freq_b, SEG, CW);
    synth_kernel<<<dim3(N_AUDIO / 256, NB), dim3(256), 0, stream>>>(SEG, CW, out);
}